// Round 7
// baseline (691.898 us; speedup 1.0000x reference)
//
#include <hip/hip_runtime.h>
#include <hip/hip_bf16.h>
#include <math.h>

#define INV_T (1.0f / 0.07f)

typedef float f32x4 __attribute__((ext_vector_type(4)));
typedef long lx2 __attribute__((ext_vector_type(2)));   // 16B = two fp8 MFMA operands

__device__ __forceinline__ void gld16(const void* g, void* l) {
    __builtin_amdgcn_global_load_lds(
        (const __attribute__((address_space(1))) unsigned int*)g,
        (__attribute__((address_space(3))) unsigned int*)l,
        16, 0, 0);
}

// ---------------- normalize + fp8 pack + positive dot + zero S/cnt ---------
__global__ __launch_bounds__(256) void norm_kernel(
    const float4* __restrict__ f1, const float4* __restrict__ f2,
    unsigned int* __restrict__ F, float* __restrict__ S, float* __restrict__ P,
    unsigned int* __restrict__ cnt, int B) {
    const int i = blockIdx.x;
    const int t = threadIdx.x;

    float4 x = f1[(size_t)i * 256 + t];
    float4 y = f2[(size_t)i * 256 + t];

    float s1 = x.x * x.x + x.y * x.y + x.z * x.z + x.w * x.w;
    float s2 = y.x * y.x + y.y * y.y + y.z * y.z + y.w * y.w;
    float dd = x.x * y.x + x.y * y.y + x.z * y.z + x.w * y.w;

    for (int o = 32; o > 0; o >>= 1) {
        s1 += __shfl_down(s1, o);
        s2 += __shfl_down(s2, o);
        dd += __shfl_down(dd, o);
    }
    __shared__ float red[4][3];
    const int wv = t >> 6, ln = t & 63;
    if (ln == 0) { red[wv][0] = s1; red[wv][1] = s2; red[wv][2] = dd; }
    __syncthreads();
    s1 = red[0][0] + red[1][0] + red[2][0] + red[3][0];
    s2 = red[0][1] + red[1][1] + red[2][1] + red[3][1];
    dd = red[0][2] + red[1][2] + red[2][2] + red[3][2];

    const float rn1 = 1.0f / fmaxf(sqrtf(s1), 1e-12f);
    const float rn2 = 1.0f / fmaxf(sqrtf(s2), 1e-12f);

    unsigned int w1 = __builtin_amdgcn_cvt_pk_fp8_f32(x.x * rn1, x.y * rn1, 0, 0);
    w1 = __builtin_amdgcn_cvt_pk_fp8_f32(x.z * rn1, x.w * rn1, w1, 1);
    F[(size_t)i * 256 + t] = w1;
    unsigned int w2 = __builtin_amdgcn_cvt_pk_fp8_f32(y.x * rn2, y.y * rn2, 0, 0);
    w2 = __builtin_amdgcn_cvt_pk_fp8_f32(y.z * rn2, y.w * rn2, w2, 1);
    F[(size_t)(B + i) * 256 + t] = w2;

    if (t == 0) {
        P[i] = dd * rn1 * rn2;
        S[i] = 0.0f;
        S[B + i] = 0.0f;
        if (i == 0) { cnt[0] = 0u; cnt[1] = 0u; }
    }
}

// ---------------- fused fp8 sim-GEMM + exp + row/col-sum + finalize --------
// 256x256 block tile, 512 threads (8 waves as 4x2 of 64x128), BK=128 fp8.
// Strictly-upper counting (gRow<gCol), exp credited to S[gRow] and S[gCol].
// Tiles: k = tj*(tj+1)/2 + ti, ti<=tj, 528 total; static 1 tile/block.
// LDS exactly 64KB (2 blocks/CU). XOR-swizzle at 16B: slot h at h^(r&7).
// Finalize scratch aliases dead As[] after the K-loop.
__global__ __launch_bounds__(512, 4) void sim_kernel(
    const unsigned char* __restrict__ F, float* __restrict__ S,
    const float* __restrict__ P, unsigned int* __restrict__ cnt,
    float* __restrict__ out, int N, int D, int B) {
    __shared__ __align__(16) unsigned char As[256][128];  // 32 KB
    __shared__ __align__(16) unsigned char Bs[256][128];  // 32 KB

    const int tid  = threadIdx.x;
    const int wave = tid >> 6;
    const int lane = tid & 63;
    const int quad = lane >> 4;
    const int l16  = lane & 15;

    const int srow   = lane >> 3;                  // row-in-8 for staging
    const int ldsOff = (lane & 7) * 16;            // dest slot bytes
    const int srcOff = ((lane & 7) ^ srow) * 16;   // swizzled source chunk

    const int waveRow = (wave >> 1) * 64;          // 0,64,128,192
    const int waveCol = (wave & 1) * 128;          // 0,128

    // ---- decode tile: k = tj*(tj+1)/2 + ti, 0 <= ti <= tj ----
    const int k = blockIdx.x;
    int tj = (int)((sqrtf(8.0f * (float)k + 1.0f) - 1.0f) * 0.5f);
    while ((tj + 1) * (tj + 2) / 2 <= k) ++tj;
    while (tj * (tj + 1) / 2 > k) --tj;
    const int ti = k - tj * (tj + 1) / 2;
    const int bRow = ti * 256;
    const int bCol = tj * 256;

    f32x4 acc[4][8];
#pragma unroll
    for (int mi = 0; mi < 4; ++mi)
#pragma unroll
        for (int ni = 0; ni < 8; ++ni)
            acc[mi][ni] = (f32x4){0.0f, 0.0f, 0.0f, 0.0f};

    for (int kb = 0; kb < D; kb += 128) {
#pragma unroll
        for (int p = 0; p < 4; ++p) {
            const int rowT = (p * 8 + wave) * 8 + srow;  // 0..255
            gld16(&F[(size_t)(bRow + rowT) * D + kb + srcOff], &As[rowT][ldsOff]);
        }
#pragma unroll
        for (int p = 0; p < 4; ++p) {
            const int rowT = (p * 8 + wave) * 8 + srow;  // 0..255
            gld16(&F[(size_t)(bCol + rowT) * D + kb + srcOff], &Bs[rowT][ldsOff]);
        }
        __syncthreads();

#pragma unroll
        for (int hf = 0; hf < 2; ++hf) {
            lx2 bfr[8];
#pragma unroll
            for (int ni = 0; ni < 8; ++ni) {
                const int r = waveCol + ni * 16 + l16;
                bfr[ni] = *(const lx2*)&Bs[r][(((quad << 1) | hf) ^ (r & 7)) * 16];
            }
            lx2 afr[4];
#pragma unroll
            for (int mi = 0; mi < 4; ++mi) {
                const int r = waveRow + mi * 16 + l16;
                afr[mi] = *(const lx2*)&As[r][(((quad << 1) | hf) ^ (r & 7)) * 16];
            }
#pragma unroll
            for (int mi = 0; mi < 4; ++mi)
#pragma unroll
                for (int ni = 0; ni < 8; ++ni) {
                    acc[mi][ni] = __builtin_amdgcn_mfma_f32_16x16x32_fp8_fp8(
                        afr[mi].x, bfr[ni].x, acc[mi][ni], 0, 0, 0);
                    acc[mi][ni] = __builtin_amdgcn_mfma_f32_16x16x32_fp8_fp8(
                        afr[mi].y, bfr[ni].y, acc[mi][ni], 0, 0, 0);
                }
        }
        __syncthreads();
    }

    // ---- epilogue: e = (gRow<gCol) ? exp((c-1)/T) : 0; row+col sums ----
#pragma unroll
    for (int mi = 0; mi < 4; ++mi)
#pragma unroll
        for (int ni = 0; ni < 8; ++ni)
#pragma unroll
            for (int r = 0; r < 4; ++r) {
                const int gRow = bRow + waveRow + mi * 16 + quad * 4 + r;
                const int gCol = bCol + waveCol + ni * 16 + l16;
                acc[mi][ni][r] = (gRow < gCol)
                    ? __expf((acc[mi][ni][r] - 1.0f) * INV_T) : 0.0f;
            }

#pragma unroll
    for (int mi = 0; mi < 4; ++mi)
#pragma unroll
        for (int r = 0; r < 4; ++r) {
            const int gRow = bRow + waveRow + mi * 16 + quad * 4 + r;
            float v = 0.0f;
#pragma unroll
            for (int ni = 0; ni < 8; ++ni) v += acc[mi][ni][r];
            v += __shfl_xor(v, 1);
            v += __shfl_xor(v, 2);
            v += __shfl_xor(v, 4);
            v += __shfl_xor(v, 8);
            if (l16 == 0) atomicAdd(&S[gRow], v);
        }

#pragma unroll
    for (int ni = 0; ni < 8; ++ni) {
        float cv = 0.0f;
#pragma unroll
        for (int mi = 0; mi < 4; ++mi)
#pragma unroll
            for (int r = 0; r < 4; ++r) cv += acc[mi][ni][r];
        cv += __shfl_xor(cv, 16);
        cv += __shfl_xor(cv, 32);
        if (quad == 0) atomicAdd(&S[bCol + waveCol + ni * 16 + l16], cv);
    }

    // ---- last-block finalize (scratch aliases dead As) ----
    __threadfence();
    volatile unsigned int* tk = (volatile unsigned int*)&As[0][0];
    float* fin = (float*)&As[0][16];   // 8 waves x 2 floats
    if (tid == 0) *tk = atomicAdd(&cnt[0], 1u);
    __syncthreads();
    if (*tk == (unsigned int)(gridDim.x - 1)) {
        __threadfence();
        volatile const float* Sv = S;
        float s = 0.0f;
        for (int i = tid; i < N; i += 512) s += __logf(Sv[i]);
        float pp = 0.0f;
        for (int i = tid; i < B; i += 512) pp += P[i];
        for (int o = 32; o > 0; o >>= 1) {
            s += __shfl_down(s, o);
            pp += __shfl_down(pp, o);
        }
        if ((tid & 63) == 0) { fin[(tid >> 6) * 2] = s; fin[(tid >> 6) * 2 + 1] = pp; }
        __syncthreads();
        if (tid == 0) {
            float sl = 0.0f, ps = 0.0f;
#pragma unroll
            for (int w = 0; w < 8; ++w) { sl += fin[w * 2]; ps += fin[w * 2 + 1]; }
            out[0] = INV_T + sl / (float)N - ps * (2.0f * INV_T / (float)N);
        }
    }
}

extern "C" void kernel_launch(void* const* d_in, const int* in_sizes, int n_in,
                              void* d_out, int out_size, void* d_ws, size_t ws_size,
                              hipStream_t stream) {
    const int D = 1024;
    const int B = in_sizes[0] / D;   // 4096
    const int N = 2 * B;             // 8192
    const int M = N / 256;           // 32 tiles per dim
    const int NT = M * (M + 1) / 2;  // 528 tiles

    const float* f1 = (const float*)d_in[0];
    const float* f2 = (const float*)d_in[1];

    unsigned char* F = (unsigned char*)d_ws;              // N*D fp8 = 8 MB
    float* S = (float*)(F + (size_t)N * D);
    float* P = S + N;                                      // B floats
    unsigned int* cnt = (unsigned int*)(P + B);            // [ticket, spare]

    norm_kernel<<<dim3(B), dim3(256), 0, stream>>>(
        (const float4*)f1, (const float4*)f2, (unsigned int*)F, S, P, cnt, B);
    sim_kernel<<<dim3(NT), dim3(512), 0, stream>>>(
        F, S, P, cnt, (float*)d_out, N, D, B);
}